// Round 3
// baseline (634.707 us; speedup 1.0000x reference)
//
#include <hip/hip_runtime.h>
#include <hip/hip_bf16.h>
#include <cstdio>

#define IN_DIM 128
#define HID 32
#define HEADS 4
#define H1DIM 128   // HEADS*HID
#define OUTD 64
#define SLOPE 0.2f

typedef __hip_bfloat16 bf16;

__device__ __forceinline__ float bf2f(bf16 v) { return __bfloat162float(v); }
__device__ __forceinline__ float lrelu(float x) { return x > 0.f ? x : SLOPE * x; }

// ---------------- dtype detectors ----------------
// flags[0]: edge_index is int64 (viewed as int32 pairs, odd slots all zero)
// flags[1]: float inputs are bf16 (low-16 of x words has concentrated bf16 exponent)
__global__ void k_detect(const int* __restrict__ ei, const unsigned int* __restrict__ xw,
                         int* __restrict__ flags) {
    __shared__ int anyNZ, cnt;
    if (threadIdx.x == 0) { anyNZ = 0; cnt = 0; }
    __syncthreads();
    if (ei[2 * threadIdx.x + 1] != 0) atomicOr(&anyNZ, 1);
    int c = 0;
    for (int k = threadIdx.x; k < 4096; k += 256) {
        unsigned e = (xw[k] >> 7) & 0xFFu;     // exponent field of low half as bf16
        if (e >= 110u && e <= 135u) c++;       // N(0,1) bf16 concentrates here
    }
    atomicAdd(&cnt, c);
    __syncthreads();
    if (threadIdx.x == 0) {
        flags[0] = (anyNZ == 0) ? 1 : 0;
        flags[1] = (cnt > 2048) ? 1 : 0;
    }
}

// ---------------- input normalization to fp32 ----------------
__global__ void k_convx(const void* __restrict__ x, float* __restrict__ xf, int total,
                        const int* __restrict__ flags) {
    int bf = flags[1];
    int i = blockIdx.x * 256 + threadIdx.x;
    int stride = gridDim.x * 256;
    if (bf) { const bf16* s = (const bf16*)x;  for (; i < total; i += stride) xf[i] = bf2f(s[i]); }
    else    { const float* s = (const float*)x; for (; i < total; i += stride) xf[i] = s[i]; }
}

struct SmallArgs { const void* src[8]; float* dst[8]; int len[8]; };
__global__ void k_convs(SmallArgs a, const int* __restrict__ flags) {
    int bf = flags[1];
    for (int k = 0; k < 8; k++) {
        int L = a.len[k];
        for (int i = blockIdx.x * 256 + threadIdx.x; i < L; i += gridDim.x * 256) {
            a.dst[k][i] = bf ? bf2f(((const bf16*)a.src[k])[i]) : ((const float*)a.src[k])[i];
        }
    }
}

// ---------------- feature kernel: h1 = x @ W1 (bf16 out), al_s1/al_d1 dots ----------------
__global__ __launch_bounds__(256) void k_feat(
    const float* __restrict__ x, const float* __restrict__ W1,
    const float* __restrict__ a_s1, const float* __restrict__ a_d1,
    bf16* __restrict__ h1, float* __restrict__ al_s, float* __restrict__ al_d, int n)
{
    __shared__ float w_lds[IN_DIM * H1DIM];   // 64 KB
    __shared__ float x_lds[2][IN_DIM];
    __shared__ float hbuf[2][H1DIM];
    __shared__ float as_lds[H1DIM], ad_lds[H1DIM];
    for (int t = threadIdx.x; t < IN_DIM * H1DIM; t += 256) w_lds[t] = W1[t];
    for (int t = threadIdx.x; t < H1DIM; t += 256) { as_lds[t] = a_s1[t]; ad_lds[t] = a_d1[t]; }
    __syncthreads();
    int sub = threadIdx.x >> 7;          // 0..1 (node within pair)
    int j   = threadIdx.x & (H1DIM - 1); // output channel
    int npairs = (n + 1) >> 1;
    for (int p = blockIdx.x; p < npairs; p += gridDim.x) {
        int i = p * 2 + sub;
        bool act = i < n;
        int ii = act ? i : (n - 1);
        __syncthreads();   // protect x_lds/hbuf from previous iteration's readers
        x_lds[sub][j] = x[(size_t)ii * IN_DIM + j];
        __syncthreads();
        float acc = 0.f;
        #pragma unroll 8
        for (int k = 0; k < IN_DIM; k++) acc = fmaf(x_lds[sub][k], w_lds[k * H1DIM + j], acc);
        if (act) h1[(size_t)i * H1DIM + j] = __float2bfloat16(acc);
        hbuf[sub][j] = acc;
        __syncthreads();
        if (threadIdx.x < 2 * HEADS) {
            int s2 = threadIdx.x >> 2, h = threadIdx.x & 3;
            float ss = 0.f, dd = 0.f;
            for (int c = 0; c < HID; c++) {
                float hv = hbuf[s2][h * HID + c];
                ss = fmaf(hv, as_lds[h * HID + c], ss);
                dd = fmaf(hv, ad_lds[h * HID + c], dd);
            }
            int node = p * 2 + s2;
            if (node < n) { al_s[node * HEADS + h] = ss; al_d[node * HEADS + h] = dd; }
        }
    }
}

// ---------------- CSR build ----------------
__global__ void k_hist(const int* __restrict__ ei, int* __restrict__ counts, int E, int n,
                       const int* __restrict__ flagp) {
    int is64 = flagp[0];
    int e = blockIdx.x * 256 + threadIdx.x;
    if (e < E) {
        int d = is64 ? ei[2 * (E + e)] : ei[E + e];
        d = min(max(d, 0), n - 1);
        atomicAdd(&counts[d], 1);
    }
}
__global__ void k_scan1(const int* __restrict__ counts, int* __restrict__ offs,
                        int* __restrict__ partials, int n) {
    __shared__ int lds[256];
    int idx = blockIdx.x * 256 + threadIdx.x;
    int v = idx < n ? counts[idx] : 0;
    lds[threadIdx.x] = v; __syncthreads();
    for (int o = 1; o < 256; o <<= 1) {
        int t = (threadIdx.x >= o) ? lds[threadIdx.x - o] : 0;
        __syncthreads(); lds[threadIdx.x] += t; __syncthreads();
    }
    if (idx < n) offs[idx] = lds[threadIdx.x] - v;     // block-local exclusive
    if (threadIdx.x == 255) partials[blockIdx.x] = lds[255];
}
__global__ void k_scan2(int* __restrict__ partials, int nb) {   // nb <= 256, 1 block
    __shared__ int lds[256];
    int v = (threadIdx.x < nb) ? partials[threadIdx.x] : 0;
    lds[threadIdx.x] = v; __syncthreads();
    for (int o = 1; o < 256; o <<= 1) {
        int t = (threadIdx.x >= o) ? lds[threadIdx.x - o] : 0;
        __syncthreads(); lds[threadIdx.x] += t; __syncthreads();
    }
    if (threadIdx.x < nb) partials[threadIdx.x] = lds[threadIdx.x] - v;  // exclusive
}
__global__ void k_scan3(int* __restrict__ offs, const int* __restrict__ partials, int n) {
    int idx = blockIdx.x * 256 + threadIdx.x;
    if (idx < n) offs[idx] += partials[blockIdx.x];
}
__global__ void k_scatter(const int* __restrict__ ei, const int* __restrict__ offs,
                          int* __restrict__ cursor, int* __restrict__ csr, int E, int n,
                          const int* __restrict__ flagp) {
    int is64 = flagp[0];
    int e = blockIdx.x * 256 + threadIdx.x;
    if (e < E) {
        int d = is64 ? ei[2 * (E + e)] : ei[E + e];
        int s = is64 ? ei[2 * e]       : ei[e];
        d = min(max(d, 0), n - 1);
        s = min(max(s, 0), n - 1);
        int pos = offs[d] + atomicAdd(&cursor[d], 1);
        if (pos >= 0 && pos < E) csr[pos] = s;
    }
}

// ---------------- layer-1 node kernel: softmax+aggregate+relu+row-GEMM(W2)+logits ----
__global__ __launch_bounds__(256) void k_node1(
    const bf16* __restrict__ h1, const float* __restrict__ al_s, const float* __restrict__ al_d,
    const int* __restrict__ csr, const int* __restrict__ offs, const int* __restrict__ counts,
    const float* __restrict__ b1, const float* __restrict__ W2,
    const float* __restrict__ a_s2, const float* __restrict__ a_d2,
    bf16* __restrict__ h2, float* __restrict__ als2, float* __restrict__ ald2, int n, int E)
{
    __shared__ float w2_lds[H1DIM * OUTD];   // 32 KB
    for (int t = threadIdx.x; t < H1DIM * OUTD; t += 256) w2_lds[t] = W2[t];
    __syncthreads();
    int wave = threadIdx.x >> 6, lane = threadIdx.x & 63;
    float as2f = a_s2[lane], ad2f = a_d2[lane];
    float b1f0 = b1[lane], b1f1 = b1[lane + 64];
    int stride = gridDim.x * 4;
    for (int i = blockIdx.x * 4 + wave; i < n; i += stride) {
        int start = offs[i], deg = counts[i];
        start = min(max(start, 0), E);
        deg = min(max(deg, 0), E - start);
        float ad0 = al_d[i * 4 + 0], ad1v = al_d[i * 4 + 1];
        float ad2v = al_d[i * 4 + 2], ad3v = al_d[i * 4 + 3];
        float4 asi = *(const float4*)(al_s + (size_t)i * 4);
        // pass 1: per-head max over incoming edges (self loop folded in)
        float m0 = lrelu(asi.x + ad0), m1 = lrelu(asi.y + ad1v);
        float m2 = lrelu(asi.z + ad2v), m3 = lrelu(asi.w + ad3v);
        for (int t = lane; t < deg; t += 64) {
            int s = csr[start + t];
            s = min(max(s, 0), n - 1);
            float4 a4 = *(const float4*)(al_s + (size_t)s * 4);
            m0 = fmaxf(m0, lrelu(a4.x + ad0));  m1 = fmaxf(m1, lrelu(a4.y + ad1v));
            m2 = fmaxf(m2, lrelu(a4.z + ad2v)); m3 = fmaxf(m3, lrelu(a4.w + ad3v));
        }
        #pragma unroll
        for (int o = 32; o; o >>= 1) {
            m0 = fmaxf(m0, __shfl_xor(m0, o)); m1 = fmaxf(m1, __shfl_xor(m1, o));
            m2 = fmaxf(m2, __shfl_xor(m2, o)); m3 = fmaxf(m3, __shfl_xor(m3, o));
        }
        // pass 2: channel-parallel aggregation. lane -> channels {lane, lane+64}
        int h0 = lane >> 5;                       // head of channel `lane` (0/1); lane+64 -> h0+2
        float mh0 = h0 ? m1 : m0, mh1 = h0 ? m3 : m2;
        float adh0 = h0 ? ad1v : ad0, adh1 = h0 ? ad3v : ad2v;
        float z0 = 0.f, z1 = 0.f, a0 = 0.f, a1 = 0.f;
        for (int t = 0; t < deg; t++) {
            int s = csr[start + t];
            s = min(max(s, 0), n - 1);
            float w0 = __expf(lrelu(al_s[s * 4 + h0] + adh0) - mh0);
            float w1 = __expf(lrelu(al_s[s * 4 + h0 + 2] + adh1) - mh1);
            z0 += w0; z1 += w1;
            const bf16* hrow = h1 + (size_t)s * H1DIM;
            a0 = fmaf(w0, bf2f(hrow[lane]), a0);
            a1 = fmaf(w1, bf2f(hrow[lane + 64]), a1);
        }
        {   // self loop
            float w0 = __expf(lrelu(al_s[i * 4 + h0] + adh0) - mh0);
            float w1 = __expf(lrelu(al_s[i * 4 + h0 + 2] + adh1) - mh1);
            z0 += w0; z1 += w1;
            const bf16* hrow = h1 + (size_t)i * H1DIM;
            a0 = fmaf(w0, bf2f(hrow[lane]), a0);
            a1 = fmaf(w1, bf2f(hrow[lane + 64]), a1);
        }
        float r0 = fmaxf(a0 / (z0 + 1e-16f) + b1f0, 0.f);
        float r1 = fmaxf(a1 / (z1 + 1e-16f) + b1f1, 0.f);
        // h2 row = r @ W2 ; broadcast r across wave via shfl
        float acc = 0.f;
        #pragma unroll 16
        for (int jj = 0; jj < 64; jj++) acc = fmaf(__shfl(r0, jj), w2_lds[jj * OUTD + lane], acc);
        #pragma unroll 16
        for (int jj = 0; jj < 64; jj++) acc = fmaf(__shfl(r1, jj), w2_lds[(64 + jj) * OUTD + lane], acc);
        h2[(size_t)i * OUTD + lane] = __float2bfloat16(acc);
        float ps = acc * as2f, pd = acc * ad2f;
        #pragma unroll
        for (int o = 32; o; o >>= 1) { ps += __shfl_xor(ps, o); pd += __shfl_xor(pd, o); }
        if (lane == 0) { als2[i] = ps; ald2[i] = pd; }
    }
}

// ---------------- layer-2 node kernel: softmax+aggregate, dtype-branched out ----------------
__global__ __launch_bounds__(256) void k_node2(
    const bf16* __restrict__ h2, const float* __restrict__ als2, const float* __restrict__ ald2,
    const int* __restrict__ csr, const int* __restrict__ offs, const int* __restrict__ counts,
    const float* __restrict__ b2, bf16* __restrict__ outb, float* __restrict__ outf,
    int n, int E, const int* __restrict__ flags)
{
    int wave = threadIdx.x >> 6, lane = threadIdx.x & 63;
    int i = blockIdx.x * 4 + wave;
    if (i >= n) return;
    int start = offs[i], deg = counts[i];
    start = min(max(start, 0), E);
    deg = min(max(deg, 0), E - start);
    float ad = ald2[i];
    float m = lrelu(als2[i] + ad);   // self loop
    for (int t = lane; t < deg; t += 64) {
        int s = csr[start + t];
        s = min(max(s, 0), n - 1);
        m = fmaxf(m, lrelu(als2[s] + ad));
    }
    #pragma unroll
    for (int o = 32; o; o >>= 1) m = fmaxf(m, __shfl_xor(m, o));
    float z = 0.f, acc = 0.f;
    for (int t = 0; t < deg; t++) {
        int s = csr[start + t];
        s = min(max(s, 0), n - 1);
        float w = __expf(lrelu(als2[s] + ad) - m);
        z += w;
        acc = fmaf(w, bf2f(h2[(size_t)s * OUTD + lane]), acc);
    }
    {   // self loop
        float w = __expf(lrelu(als2[i] + ad) - m);
        z += w;
        acc = fmaf(w, bf2f(h2[(size_t)i * OUTD + lane]), acc);
    }
    float v = acc / (z + 1e-16f) + b2[lane];
    if (flags[1]) outb[(size_t)i * OUTD + lane] = __float2bfloat16(v);
    else          outf[(size_t)i * OUTD + lane] = v;
}

extern "C" void kernel_launch(void* const* d_in, const int* in_sizes, int n_in,
                              void* d_out, int out_size, void* d_ws, size_t ws_size,
                              hipStream_t stream)
{
    const void* x    = d_in[0];
    const int*  ei   = (const int*)d_in[1];
    // d_in[2] = edge_attr (ignored)
    int n = in_sizes[0] / IN_DIM;     // 50000
    int E = in_sizes[1] / 2;          // 800000

    // ---- workspace layout ----
    size_t sz_xf   = (size_t)n * IN_DIM * sizeof(float);  // 25.6 MB
    size_t sz_w1   = IN_DIM * H1DIM * sizeof(float);      // 64 KB
    size_t sz_w2   = H1DIM * OUTD * sizeof(float);        // 32 KB
    size_t sz_v128 = H1DIM * sizeof(float);               // 512 B
    size_t sz_v64  = OUTD * sizeof(float);                // 256 B
    size_t sz_h1   = (size_t)n * H1DIM * sizeof(bf16);    // 12.8 MB
    size_t sz_h2   = (size_t)n * OUTD * sizeof(bf16);     //  6.4 MB
    size_t sz_al1  = (size_t)n * HEADS * sizeof(float);   //  0.8 MB (x2)
    size_t sz_al2  = (size_t)n * sizeof(float);           //  0.2 MB (x2)
    size_t sz_int  = (size_t)n * sizeof(int);             //  0.2 MB (x3)
    size_t sz_part = 4096;
    size_t sz_csr  = (size_t)E * sizeof(int);             //  3.2 MB
    size_t need = sz_xf + sz_w1 + sz_w2 + 3 * sz_v128 + 3 * sz_v64 + sz_h1 + sz_h2
                + 2 * sz_al1 + 2 * sz_al2 + 3 * sz_int + sz_part + sz_csr;

    fprintf(stderr, "[GAT] ws_size=%zu need=%zu n=%d E=%d n_in=%d out_size=%d\n",
            ws_size, need, n, E, n_in, out_size);
    if (ws_size < need) { hipMemsetAsync(d_out, 0, (size_t)out_size * 2, stream); return; }

    char* p = (char*)d_ws;
    float* xf    = (float*)p; p += sz_xf;
    float* wf1   = (float*)p; p += sz_w1;
    float* wf2   = (float*)p; p += sz_w2;
    float* asf1  = (float*)p; p += sz_v128;
    float* adf1  = (float*)p; p += sz_v128;
    float* b1f   = (float*)p; p += sz_v128;
    float* as2f  = (float*)p; p += sz_v64;
    float* ad2f  = (float*)p; p += sz_v64;
    float* b2f   = (float*)p; p += sz_v64;
    bf16*  h1    = (bf16*)p;  p += sz_h1;
    bf16*  h2    = (bf16*)p;  p += sz_h2;
    float* als1  = (float*)p; p += sz_al1;
    float* ald1  = (float*)p; p += sz_al1;
    float* als2  = (float*)p; p += sz_al2;
    float* ald2  = (float*)p; p += sz_al2;
    int* counts  = (int*)p;   p += sz_int;
    int* cursor  = (int*)p;   p += sz_int;   // adjacent to counts -> one memset
    int* offs    = (int*)p;   p += sz_int;
    int* partials= (int*)p;   p += sz_part;  // partials[0..255]; flags at partials[512..]
    int* flags   = partials + 512;
    int* csr     = (int*)p;

    hipMemsetAsync(counts, 0, 2 * sz_int, stream);   // counts + cursor

    SmallArgs sa;
    sa.src[0] = d_in[3]; sa.dst[0] = wf1;  sa.len[0] = IN_DIM * H1DIM;
    sa.src[1] = d_in[4]; sa.dst[1] = asf1; sa.len[1] = H1DIM;
    sa.src[2] = d_in[5]; sa.dst[2] = adf1; sa.len[2] = H1DIM;
    sa.src[3] = d_in[6]; sa.dst[3] = b1f;  sa.len[3] = H1DIM;
    sa.src[4] = d_in[7]; sa.dst[4] = wf2;  sa.len[4] = H1DIM * OUTD;
    sa.src[5] = d_in[8]; sa.dst[5] = as2f; sa.len[5] = OUTD;
    sa.src[6] = d_in[9]; sa.dst[6] = ad2f; sa.len[6] = OUTD;
    sa.src[7] = d_in[10]; sa.dst[7] = b2f; sa.len[7] = OUTD;

    int nb = (n + 255) / 256;                         // 196 (<=256 for k_scan2)
    k_detect<<<1, 256, 0, stream>>>(ei, (const unsigned int*)x, flags);
    k_convx<<<8192, 256, 0, stream>>>(x, xf, n * IN_DIM, flags);
    k_convs<<<32, 256, 0, stream>>>(sa, flags);
    k_feat<<<1024, 256, 0, stream>>>(xf, wf1, asf1, adf1, h1, als1, ald1, n);
    k_hist<<<(E + 255) / 256, 256, 0, stream>>>(ei, counts, E, n, flags);
    k_scan1<<<nb, 256, 0, stream>>>(counts, offs, partials, n);
    k_scan2<<<1, 256, 0, stream>>>(partials, nb);
    k_scan3<<<nb, 256, 0, stream>>>(offs, partials, n);
    k_scatter<<<(E + 255) / 256, 256, 0, stream>>>(ei, offs, cursor, csr, E, n, flags);
    k_node1<<<1600, 256, 0, stream>>>(h1, als1, ald1, csr, offs, counts,
                                      b1f, wf2, as2f, ad2f, h2, als2, ald2, n, E);
    k_node2<<<(n + 3) / 4, 256, 0, stream>>>(h2, als2, ald2, csr, offs, counts,
                                             b2f, (bf16*)d_out, (float*)d_out, n, E, flags);
}

// Round 4
// 477.912 us; speedup vs baseline: 1.3281x; 1.3281x over previous
//
#include <hip/hip_runtime.h>
#include <hip/hip_bf16.h>

#define IN_DIM 128
#define HID 32
#define HEADS 4
#define H1DIM 128   // HEADS*HID
#define OUTD 64
#define SLOPE 0.2f

typedef __hip_bfloat16 bf16;
typedef unsigned int uint32;

__device__ __forceinline__ float bf2f(bf16 v) { return __bfloat162float(v); }
__device__ __forceinline__ float lrelu(float x) { return x > 0.f ? x : SLOPE * x; }
__device__ __forceinline__ float lo16(uint32 u) { return __uint_as_float(u << 16); }
__device__ __forceinline__ float hi16(uint32 u) { return __uint_as_float(u & 0xffff0000u); }
__device__ __forceinline__ uint32 packbf(float a, float b) {
    bf16 x = __float2bfloat16(a), y = __float2bfloat16(b);
    unsigned short ux = __builtin_bit_cast(unsigned short, x);
    unsigned short uy = __builtin_bit_cast(unsigned short, y);
    return (uint32)ux | ((uint32)uy << 16);
}

// ---------------- dtype detectors ----------------
// flags[0]: edge_index is int64 (viewed as int32 pairs, odd slots all zero)
// flags[1]: float inputs are bf16 (low-16 of x words has concentrated bf16 exponent)
__global__ void k_detect(const int* __restrict__ ei, const uint32* __restrict__ xw,
                         int* __restrict__ flags) {
    __shared__ int anyNZ, cnt;
    if (threadIdx.x == 0) { anyNZ = 0; cnt = 0; }
    __syncthreads();
    if (ei[2 * threadIdx.x + 1] != 0) atomicOr(&anyNZ, 1);
    int c = 0;
    for (int k = threadIdx.x; k < 4096; k += 256) {
        unsigned e = (xw[k] >> 7) & 0xFFu;     // exponent field of low half as bf16
        if (e >= 110u && e <= 135u) c++;       // N(0,1) bf16 concentrates here
    }
    atomicAdd(&cnt, c);
    __syncthreads();
    if (threadIdx.x == 0) {
        flags[0] = (anyNZ == 0) ? 1 : 0;
        flags[1] = (cnt > 2048) ? 1 : 0;
    }
}

// ---------------- input normalization to fp32 ----------------
__global__ void k_convx(const void* __restrict__ x, float* __restrict__ xf, int total,
                        const int* __restrict__ flags) {
    int bf = flags[1];
    int i = blockIdx.x * 256 + threadIdx.x;
    int stride = gridDim.x * 256;
    if (bf) { const bf16* s = (const bf16*)x;  for (; i < total; i += stride) xf[i] = bf2f(s[i]); }
    else    { const float* s = (const float*)x; for (; i < total; i += stride) xf[i] = s[i]; }
}

struct SmallArgs { const void* src[8]; float* dst[8]; int len[8]; };
__global__ void k_convs(SmallArgs a, const int* __restrict__ flags) {
    int bf = flags[1];
    for (int k = 0; k < 8; k++) {
        int L = a.len[k];
        for (int i = blockIdx.x * 256 + threadIdx.x; i < L; i += gridDim.x * 256) {
            a.dst[k][i] = bf ? bf2f(((const bf16*)a.src[k])[i]) : ((const float*)a.src[k])[i];
        }
    }
}

// ---------------- feature kernel: h1 = x @ W1 (bf16 out), al_s1/al_d1 dots ----------------
__global__ __launch_bounds__(256) void k_feat(
    const float* __restrict__ x, const float* __restrict__ W1,
    const float* __restrict__ a_s1, const float* __restrict__ a_d1,
    bf16* __restrict__ h1, float* __restrict__ al_s, float* __restrict__ al_d, int n)
{
    __shared__ float w_lds[IN_DIM * H1DIM];   // 64 KB
    __shared__ float x_lds[2][IN_DIM];
    __shared__ float hbuf[2][H1DIM];
    __shared__ float as_lds[H1DIM], ad_lds[H1DIM];
    for (int t = threadIdx.x; t < IN_DIM * H1DIM; t += 256) w_lds[t] = W1[t];
    for (int t = threadIdx.x; t < H1DIM; t += 256) { as_lds[t] = a_s1[t]; ad_lds[t] = a_d1[t]; }
    __syncthreads();
    int sub = threadIdx.x >> 7;          // 0..1 (node within pair)
    int j   = threadIdx.x & (H1DIM - 1); // output channel
    int npairs = (n + 1) >> 1;
    for (int p = blockIdx.x; p < npairs; p += gridDim.x) {
        int i = p * 2 + sub;
        bool act = i < n;
        int ii = act ? i : (n - 1);
        __syncthreads();   // protect x_lds/hbuf from previous iteration's readers
        x_lds[sub][j] = x[(size_t)ii * IN_DIM + j];
        __syncthreads();
        float acc = 0.f;
        #pragma unroll 8
        for (int k = 0; k < IN_DIM; k++) acc = fmaf(x_lds[sub][k], w_lds[k * H1DIM + j], acc);
        if (act) h1[(size_t)i * H1DIM + j] = __float2bfloat16(acc);
        hbuf[sub][j] = acc;
        __syncthreads();
        if (threadIdx.x < 2 * HEADS) {
            int s2 = threadIdx.x >> 2, h = threadIdx.x & 3;
            float ss = 0.f, dd = 0.f;
            for (int c = 0; c < HID; c++) {
                float hv = hbuf[s2][h * HID + c];
                ss = fmaf(hv, as_lds[h * HID + c], ss);
                dd = fmaf(hv, ad_lds[h * HID + c], dd);
            }
            int node = p * 2 + s2;
            if (node < n) { al_s[node * HEADS + h] = ss; al_d[node * HEADS + h] = dd; }
        }
    }
}

// ---------------- CSR build ----------------
__global__ void k_hist(const int* __restrict__ ei, int* __restrict__ counts, int E, int n,
                       const int* __restrict__ flagp) {
    int is64 = flagp[0];
    int e = blockIdx.x * 256 + threadIdx.x;
    if (e < E) {
        int d = is64 ? ei[2 * (E + e)] : ei[E + e];
        d = min(max(d, 0), n - 1);
        atomicAdd(&counts[d], 1);
    }
}
__global__ void k_scan1(const int* __restrict__ counts, int* __restrict__ offs,
                        int* __restrict__ partials, int n) {
    __shared__ int lds[256];
    int idx = blockIdx.x * 256 + threadIdx.x;
    int v = idx < n ? counts[idx] : 0;
    lds[threadIdx.x] = v; __syncthreads();
    for (int o = 1; o < 256; o <<= 1) {
        int t = (threadIdx.x >= o) ? lds[threadIdx.x - o] : 0;
        __syncthreads(); lds[threadIdx.x] += t; __syncthreads();
    }
    if (idx < n) offs[idx] = lds[threadIdx.x] - v;     // block-local exclusive
    if (threadIdx.x == 255) partials[blockIdx.x] = lds[255];
}
__global__ void k_scan2(int* __restrict__ partials, int nb) {   // nb <= 256, 1 block
    __shared__ int lds[256];
    int v = (threadIdx.x < nb) ? partials[threadIdx.x] : 0;
    lds[threadIdx.x] = v; __syncthreads();
    for (int o = 1; o < 256; o <<= 1) {
        int t = (threadIdx.x >= o) ? lds[threadIdx.x - o] : 0;
        __syncthreads(); lds[threadIdx.x] += t; __syncthreads();
    }
    if (threadIdx.x < nb) partials[threadIdx.x] = lds[threadIdx.x] - v;  // exclusive
}
__global__ void k_scan3(int* __restrict__ offs, const int* __restrict__ partials, int n) {
    int idx = blockIdx.x * 256 + threadIdx.x;
    if (idx < n) offs[idx] += partials[blockIdx.x];
}
__global__ void k_scatter(const int* __restrict__ ei, const int* __restrict__ offs,
                          int* __restrict__ cursor, int* __restrict__ csr, int E, int n,
                          const int* __restrict__ flagp) {
    int is64 = flagp[0];
    int e = blockIdx.x * 256 + threadIdx.x;
    if (e < E) {
        int d = is64 ? ei[2 * (E + e)] : ei[E + e];
        int s = is64 ? ei[2 * e]       : ei[e];
        d = min(max(d, 0), n - 1);
        s = min(max(s, 0), n - 1);
        int pos = offs[d] + atomicAdd(&cursor[d], 1);
        if (pos >= 0 && pos < E) csr[pos] = s;
    }
}

// ---------------- layer-1 aggregation (no max pass, channel-packed) ----------------
// wave per node; lane owns channels {2*lane, 2*lane+1} (same head = lane>>4).
// Phase A (lane-parallel): weights for 64 edges -> LDS. Phase B (serial): 2 LDS reads
// + 1 packed uint load + 2 fma per edge, no dependent-load chain.
__global__ __launch_bounds__(256) void k_agg1(
    const uint32* __restrict__ h1u, const float* __restrict__ al_s, const float* __restrict__ al_d,
    const int* __restrict__ csr, const int* __restrict__ offs, const int* __restrict__ counts,
    const float* __restrict__ b1, uint32* __restrict__ r_u, int n, int E)
{
    __shared__ int   s_lds[4][64];
    __shared__ float w_lds[4][64 * 4];
    __shared__ int totsh[4];
    int wave = threadIdx.x >> 6, lane = threadIdx.x & 63;
    int i = blockIdx.x * 4 + wave;
    bool live = i < n;
    int ii = live ? i : 0;
    int start = 0, deg = 0, tot = 0;
    float4 adv = make_float4(0.f, 0.f, 0.f, 0.f);
    if (live) {
        start = offs[ii]; deg = counts[ii];
        start = min(max(start, 0), E); deg = min(max(deg, 0), E - start);
        tot = deg + 1;                                   // + self loop
        adv = *(const float4*)(al_d + 4 * (size_t)ii);
    }
    if (lane == 0) totsh[wave] = tot;
    __syncthreads();
    int maxtot = max(max(totsh[0], totsh[1]), max(totsh[2], totsh[3]));
    int head = lane >> 4;
    float z0 = 0.f, z1 = 0.f, z2 = 0.f, z3 = 0.f, a0 = 0.f, a1 = 0.f;
    for (int base = 0; base < maxtot; base += 64) {
        int t = base + lane;
        int s = ii;
        if (t < deg) { int c = csr[start + t]; s = min(max(c, 0), n - 1); }
        float w0 = 0.f, w1 = 0.f, w2 = 0.f, w3 = 0.f;
        if (live && t < tot) {
            float4 as4 = *(const float4*)(al_s + 4 * (size_t)s);
            w0 = __expf(lrelu(as4.x + adv.x));
            w1 = __expf(lrelu(as4.y + adv.y));
            w2 = __expf(lrelu(as4.z + adv.z));
            w3 = __expf(lrelu(as4.w + adv.w));
        }
        z0 += w0; z1 += w1; z2 += w2; z3 += w3;
        s_lds[wave][lane] = s;
        *(float4*)&w_lds[wave][lane * 4] = make_float4(w0, w1, w2, w3);
        __syncthreads();
        int m = min(64, tot - base);
        #pragma unroll 4
        for (int j = 0; j < m; j++) {
            int   sj = s_lds[wave][j];
            float wj = w_lds[wave][j * 4 + head];
            uint32 hv = h1u[(size_t)sj * 64 + lane];
            a0 = fmaf(wj, lo16(hv), a0);
            a1 = fmaf(wj, hi16(hv), a1);
        }
        __syncthreads();
    }
    #pragma unroll
    for (int o = 32; o; o >>= 1) {
        z0 += __shfl_xor(z0, o); z1 += __shfl_xor(z1, o);
        z2 += __shfl_xor(z2, o); z3 += __shfl_xor(z3, o);
    }
    if (live) {
        float zz = head == 0 ? z0 : head == 1 ? z1 : head == 2 ? z2 : z3;
        float inv = 1.f / (zz + 1e-16f);
        float r0 = fmaxf(a0 * inv + b1[2 * lane], 0.f);      // + bias, ReLU
        float r1 = fmaxf(a1 * inv + b1[2 * lane + 1], 0.f);
        r_u[(size_t)i * 64 + lane] = packbf(r0, r1);
    }
}

// ---------------- layer-2 feature GEMM: h2 = r @ W2, als2/ald2 dots ----------------
__global__ __launch_bounds__(256) void k_gemm2(
    const uint32* __restrict__ r_u, const float* __restrict__ W2,
    const float* __restrict__ a_s2, const float* __restrict__ a_d2,
    bf16* __restrict__ h2, float* __restrict__ als2, float* __restrict__ ald2, int n)
{
    __shared__ float w2_lds[H1DIM * OUTD];   // 32 KB
    for (int t = threadIdx.x; t < H1DIM * OUTD; t += 256) w2_lds[t] = W2[t];
    __syncthreads();
    int wave = threadIdx.x >> 6, lane = threadIdx.x & 63;
    int i = blockIdx.x * 4 + wave;
    if (i >= n) return;
    uint32 rv = r_u[(size_t)i * 64 + lane];
    float acc = 0.f;
    #pragma unroll 8
    for (int t = 0; t < 64; t++) {
        uint32 rb = __shfl(rv, t);
        acc = fmaf(lo16(rb), w2_lds[(2 * t) * OUTD + lane], acc);
        acc = fmaf(hi16(rb), w2_lds[(2 * t + 1) * OUTD + lane], acc);
    }
    h2[(size_t)i * OUTD + lane] = __float2bfloat16(acc);
    float ps = acc * a_s2[lane], pd = acc * a_d2[lane];
    #pragma unroll
    for (int o = 32; o; o >>= 1) { ps += __shfl_xor(ps, o); pd += __shfl_xor(pd, o); }
    if (lane == 0) { als2[i] = ps; ald2[i] = pd; }
}

// ---------------- layer-2 aggregation (no max pass) ----------------
__global__ __launch_bounds__(256) void k_agg2(
    const bf16* __restrict__ h2, const float* __restrict__ als2, const float* __restrict__ ald2,
    const int* __restrict__ csr, const int* __restrict__ offs, const int* __restrict__ counts,
    const float* __restrict__ b2, bf16* __restrict__ outb, float* __restrict__ outf,
    int n, int E, const int* __restrict__ flags)
{
    __shared__ int   s_lds[4][64];
    __shared__ float w_lds[4][64];
    __shared__ int totsh[4];
    int wave = threadIdx.x >> 6, lane = threadIdx.x & 63;
    int i = blockIdx.x * 4 + wave;
    bool live = i < n;
    int ii = live ? i : 0;
    int start = 0, deg = 0, tot = 0;
    float ad = 0.f;
    if (live) {
        start = offs[ii]; deg = counts[ii];
        start = min(max(start, 0), E); deg = min(max(deg, 0), E - start);
        tot = deg + 1;
        ad = ald2[ii];
    }
    if (lane == 0) totsh[wave] = tot;
    __syncthreads();
    int maxtot = max(max(totsh[0], totsh[1]), max(totsh[2], totsh[3]));
    float z = 0.f, a = 0.f;
    for (int base = 0; base < maxtot; base += 64) {
        int t = base + lane;
        int s = ii;
        if (t < deg) { int c = csr[start + t]; s = min(max(c, 0), n - 1); }
        float w = 0.f;
        if (live && t < tot) w = __expf(lrelu(als2[s] + ad));
        z += w;
        s_lds[wave][lane] = s;
        w_lds[wave][lane] = w;
        __syncthreads();
        int m = min(64, tot - base);
        #pragma unroll 4
        for (int j = 0; j < m; j++) {
            int   sj = s_lds[wave][j];
            float wj = w_lds[wave][j];
            a = fmaf(wj, bf2f(h2[(size_t)sj * OUTD + lane]), a);
        }
        __syncthreads();
    }
    #pragma unroll
    for (int o = 32; o; o >>= 1) z += __shfl_xor(z, o);
    if (live) {
        float v = a / (z + 1e-16f) + b2[lane];
        if (flags[1]) outb[(size_t)i * OUTD + lane] = __float2bfloat16(v);
        else          outf[(size_t)i * OUTD + lane] = v;
    }
}

extern "C" void kernel_launch(void* const* d_in, const int* in_sizes, int n_in,
                              void* d_out, int out_size, void* d_ws, size_t ws_size,
                              hipStream_t stream)
{
    (void)n_in;
    const void* x  = d_in[0];
    const int*  ei = (const int*)d_in[1];
    // d_in[2] = edge_attr (ignored)
    int n = in_sizes[0] / IN_DIM;     // 50000
    int E = in_sizes[1] / 2;          // 800000

    // ---- workspace layout ----
    size_t sz_xf   = (size_t)n * IN_DIM * sizeof(float);  // 25.6 MB
    size_t sz_w1   = IN_DIM * H1DIM * sizeof(float);
    size_t sz_w2   = H1DIM * OUTD * sizeof(float);
    size_t sz_v128 = H1DIM * sizeof(float);
    size_t sz_v64  = OUTD * sizeof(float);
    size_t sz_h1   = (size_t)n * H1DIM * sizeof(bf16);    // 12.8 MB
    size_t sz_r    = (size_t)n * H1DIM * sizeof(bf16);    // 12.8 MB
    size_t sz_h2   = (size_t)n * OUTD * sizeof(bf16);     //  6.4 MB
    size_t sz_al1  = (size_t)n * HEADS * sizeof(float);
    size_t sz_al2  = (size_t)n * sizeof(float);
    size_t sz_int  = (size_t)n * sizeof(int);
    size_t sz_part = 4096;
    size_t sz_csr  = (size_t)E * sizeof(int);             //  3.2 MB
    size_t need = sz_xf + sz_w1 + sz_w2 + 3 * sz_v128 + 3 * sz_v64 + sz_h1 + sz_r + sz_h2
                + 2 * sz_al1 + 2 * sz_al2 + 3 * sz_int + sz_part + sz_csr;
    if (ws_size < need) { hipMemsetAsync(d_out, 0, (size_t)out_size * 2, stream); return; }

    char* p = (char*)d_ws;
    float* xf    = (float*)p; p += sz_xf;
    float* wf1   = (float*)p; p += sz_w1;
    float* wf2   = (float*)p; p += sz_w2;
    float* asf1  = (float*)p; p += sz_v128;
    float* adf1  = (float*)p; p += sz_v128;
    float* b1f   = (float*)p; p += sz_v128;
    float* as2f  = (float*)p; p += sz_v64;
    float* ad2f  = (float*)p; p += sz_v64;
    float* b2f   = (float*)p; p += sz_v64;
    bf16*  h1    = (bf16*)p;  p += sz_h1;
    uint32* r_u  = (uint32*)p; p += sz_r;
    bf16*  h2    = (bf16*)p;  p += sz_h2;
    float* als1  = (float*)p; p += sz_al1;
    float* ald1  = (float*)p; p += sz_al1;
    float* als2  = (float*)p; p += sz_al2;
    float* ald2  = (float*)p; p += sz_al2;
    int* counts  = (int*)p;   p += sz_int;
    int* cursor  = (int*)p;   p += sz_int;   // adjacent to counts -> one memset
    int* offs    = (int*)p;   p += sz_int;
    int* partials= (int*)p;   p += sz_part;  // partials[0..255]; flags at partials[512..]
    int* flags   = partials + 512;
    int* csr     = (int*)p;

    hipMemsetAsync(counts, 0, 2 * sz_int, stream);   // counts + cursor

    SmallArgs sa;
    sa.src[0] = d_in[3];  sa.dst[0] = wf1;  sa.len[0] = IN_DIM * H1DIM;
    sa.src[1] = d_in[4];  sa.dst[1] = asf1; sa.len[1] = H1DIM;
    sa.src[2] = d_in[5];  sa.dst[2] = adf1; sa.len[2] = H1DIM;
    sa.src[3] = d_in[6];  sa.dst[3] = b1f;  sa.len[3] = H1DIM;
    sa.src[4] = d_in[7];  sa.dst[4] = wf2;  sa.len[4] = H1DIM * OUTD;
    sa.src[5] = d_in[8];  sa.dst[5] = as2f; sa.len[5] = OUTD;
    sa.src[6] = d_in[9];  sa.dst[6] = ad2f; sa.len[6] = OUTD;
    sa.src[7] = d_in[10]; sa.dst[7] = b2f;  sa.len[7] = OUTD;

    int nb  = (n + 255) / 256;    // 196 (<=256 for k_scan2)
    int nb4 = (n + 3) / 4;        // 12500
    int nbe = (E + 255) / 256;
    k_detect<<<1, 256, 0, stream>>>(ei, (const uint32*)x, flags);
    k_convx<<<4096, 256, 0, stream>>>(x, xf, n * IN_DIM, flags);
    k_convs<<<32, 256, 0, stream>>>(sa, flags);
    k_feat<<<1024, 256, 0, stream>>>(xf, wf1, asf1, adf1, h1, als1, ald1, n);
    k_hist<<<nbe, 256, 0, stream>>>(ei, counts, E, n, flags);
    k_scan1<<<nb, 256, 0, stream>>>(counts, offs, partials, n);
    k_scan2<<<1, 256, 0, stream>>>(partials, nb);
    k_scan3<<<nb, 256, 0, stream>>>(offs, partials, n);
    k_scatter<<<nbe, 256, 0, stream>>>(ei, offs, cursor, csr, E, n, flags);
    k_agg1<<<nb4, 256, 0, stream>>>((const uint32*)h1, als1, ald1, csr, offs, counts,
                                    b1f, r_u, n, E);
    k_gemm2<<<nb4, 256, 0, stream>>>(r_u, wf2, as2f, ad2f, h2, als2, ald2, n);
    k_agg2<<<nb4, 256, 0, stream>>>(h2, als2, ald2, csr, offs, counts,
                                    b2f, (bf16*)d_out, (float*)d_out, n, E, flags);
}